// Round 1
// 215.374 us; speedup vs baseline: 1.0204x; 1.0204x over previous
//
#include <hip/hip_runtime.h>

// Born-series scattering, fully fused recompute-G approach.
// M=4096 pts, 4 wavenumbers (0.5,1,1.5,2), 5 Born iterations, 64 obs dirs.
// R4: bit-faithful D^2 (Gram rounding sequence) -> absmax 0.0.
// R5-R8: atomics eliminated; fused chunk-reduce.
// R9-R15: eight probes on the ~25us matvec plateau (packed math, s_load
//   promotion, row-pair ILP, LDS pipeline, manual phasing, 2x residency,
//   2x chunks) all neutral or regressed. The body's serial
//   load->D2->rsq->sincos->recurrence chain is trans-pipe-bound; extra
//   waves collide on the shared quarter-rate trans pipe (R15 proof).
// R16: best-measured config (R14, 219.8us).
// R17: latency-bound small kernels parallelized (matvec untouched, bit-exact):
//   - reduce_update_k: was 256 waves total (0.25/SIMD), 16 serially-dependent
//     load batches. Now 8 lanes per (n,row) -> 2048 waves; each thread owns
//     one of the 8 mod-8 accumulators (same sequential order), then the exact
//     ((s0+s1)+(s2+s3))+((s4+s5)+(s6+s7)) tree via 3x shfl_xor (fp add is
//     bitwise-commutative -> identical rounding).
//   - init_k: 16x256 -> 64x64 (spread across 64 CUs).
//
// ws layout (floats):
//   colpack[M][12]: x,y,z,r2, ar[4], ai[4]          (a = C * vw * psi, per k)
//   cvw[M]; p0r[4][M], p0i[4][M]; yr[4][M], yi[4][M] (fallback)
//   part[C][4][M] of float2                          (partials, 16MB)

#define MM 4096
#define NK 4
#define CGREEN 0.07957747154594767f   // 1/(4*pi)
#define INV2PI 0.15915494309189535f   // 1/(2*pi)

#define OFF_VW   49152
#define OFF_P0R  53248
#define OFF_P0I  69632
#define OFF_YR   86016
#define OFF_YI   102400
#define OFF_PART 118784
#define NCHUNK 128
#define PART_FLOATS (NCHUNK * 8 * MM)
#define WS_NEED_PART ((size_t)(OFF_PART + PART_FLOATS) * 4)

typedef float f2 __attribute__((ext_vector_type(2)));

__device__ __forceinline__ f2 vfma(f2 a, f2 b, f2 c) {
    f2 r; r.x = fmaf(a.x, b.x, c.x); r.y = fmaf(a.y, b.y, c.y); return r;
}

__global__ __launch_bounds__(64) void init_k(const float* __restrict__ V,
                                             const float* __restrict__ pts,
                                             const float* __restrict__ w,
                                             float* __restrict__ ws) {
#pragma clang fp contract(off)
    int i = blockIdx.x * 64 + threadIdx.x;
    float x = pts[3 * i], y = pts[3 * i + 1], z = pts[3 * i + 2];
    float cvw = CGREEN * (V[i] * w[i]);
    float xx = x * x, yy = y * y, zz = z * z;
    float r2 = (xx + yy) + zz;                 // np rounding order
    float* cp = ws + i * 12;
    cp[0] = x; cp[1] = y; cp[2] = z; cp[3] = r2;
    ws[OFF_VW + i] = cvw;
#pragma unroll
    for (int n = 0; n < NK; n++) {
        float kk = 0.5f * (float)(n + 1);
        float s, c;
        sincosf(kk * z, &s, &c);
        ws[OFF_P0R + n * MM + i] = c;
        ws[OFF_P0I + n * MM + i] = s;
        cp[4 + n] = cvw * c;
        cp[8 + n] = cvw * s;
        ws[OFF_YR + n * MM + i] = 0.0f;
        ws[OFF_YI + n * MM + i] = 0.0f;
    }
}

// One column vs TWO rows; D^2/trans/recurrence packed across the row pair.
__device__ __forceinline__ void body_col2(f2 rx, f2 ry, f2 rz, f2 rr2,
                                          int r0, int r1, int jg,
                                          float4 A, float4 R, float4 I,
                                          f2 acc0[4], f2 acc1[4]) {
    // ---- bit-faithful D^2, per-element rounding == reference sequence ----
    f2 d2;
    {
#pragma clang fp contract(off)
        f2 m; m.x = rx.x * A.x; m.y = rx.y * A.x;          // rounded mul
        m = vfma(ry, (f2){A.y, A.y}, m);                   // k-order fma chain
        m = vfma(rz, (f2){A.z, A.z}, m);
        f2 r2s = rr2 + A.w;                                // rounded add
        f2 twod = 2.0f * m;                                // exact
        d2 = r2s - twod;                                   // single rounded sub
    }
    d2.x = fmaxf(d2.x, 1e-12f);
    d2.y = fmaxf(d2.y, 1e-12f);
    // ---- fast-math (proven invisible in bucketed output) ----
    float ia = __builtin_amdgcn_rsqf(d2.x);
    float ib = __builtin_amdgcn_rsqf(d2.y);
    f2 invD = {ia, ib};
    f2 rev = d2 * invD * (0.5f * INV2PI);   // angle 0.5*D in revolutions
    float sca = (jg == r0) ? 0.0f : ia;
    float scb = (jg == r1) ? 0.0f : ib;
    f2 s1, c1;
    s1.x = __builtin_amdgcn_sinf(rev.x);    // raw v_sin: sin(2*pi*x)
    c1.x = __builtin_amdgcn_cosf(rev.x);
    s1.y = __builtin_amdgcn_sinf(rev.y);
    c1.y = __builtin_amdgcn_cosf(rev.y);
    f2 c2 = vfma(c1, c1, -(s1 * s1));
    f2 s2 = 2.0f * (c1 * s1);
    f2 c3 = vfma(c2, c1, -(s2 * s1));
    f2 s3 = vfma(s2, c1, c2 * s1);
    f2 c4 = vfma(c2, c2, -(s2 * s2));
    f2 s4 = 2.0f * (c2 * s2);
#define ACC_UPD(nn, CC, SS, ZR, ZI)                                          \
    {                                                                        \
        f2 ri = {ZR, ZI}, sw = {-ZI, ZR};                                    \
        f2 t0 = CC.x * ri; t0 = vfma((f2){SS.x, SS.x}, sw, t0);              \
        acc0[nn] = vfma((f2){sca, sca}, t0, acc0[nn]);                       \
        f2 t1 = CC.y * ri; t1 = vfma((f2){SS.y, SS.y}, sw, t1);              \
        acc1[nn] = vfma((f2){scb, scb}, t1, acc1[nn]);                       \
    }
    ACC_UPD(0, c1, s1, R.x, I.x)
    ACC_UPD(1, c2, s2, R.y, I.y)
    ACC_UPD(2, c3, s3, R.z, I.z)
    ACC_UPD(3, c4, s4, R.w, I.w)
#undef ACC_UPD
}

// grid: (C chunks, 8 row-groups of 512); block 256; 2 rows/thread.
template <int C, bool USE_PART>
__global__ __launch_bounds__(256) void matvec_k(const float* __restrict__ cols,
                                                f2* __restrict__ part,
                                                float* __restrict__ yr,
                                                float* __restrict__ yi) {
    constexpr int TC = MM / C;                 // cols per block (32)
    const int chunk = blockIdx.x;
    const int rg = blockIdx.y;
    const int r0 = rg * 512 + threadIdx.x;
    const int r1 = r0 + 256;
    const float4 rowA = *(const float4*)&cols[r0 * 12];   // x,y,z,r2
    const float4 rowB = *(const float4*)&cols[r1 * 12];
    const f2 rx = {rowA.x, rowB.x}, ry = {rowA.y, rowB.y};
    const f2 rz = {rowA.z, rowB.z}, rr2 = {rowA.w, rowB.w};
    f2 acc0[4], acc1[4];
#pragma unroll
    for (int i = 0; i < 4; i++) {
        acc0[i].x = 0.0f; acc0[i].y = 0.0f;
        acc1[i].x = 0.0f; acc1[i].y = 0.0f;
    }
    const int jg0 = chunk * TC;
    const float* colbase = cols + (size_t)jg0 * 12;   // uniform across lanes
#pragma unroll 4
    for (int j = 0; j < TC; j++) {
        const float4* cp = (const float4*)(colbase + j * 12);
        float4 A = cp[0], R = cp[1], I = cp[2];
        body_col2(rx, ry, rz, rr2, r0, r1, jg0 + j, A, R, I, acc0, acc1);
    }
    if (USE_PART) {
#pragma unroll
        for (int n = 0; n < NK; n++) {
            part[(size_t)(chunk * 4 + n) * MM + r0] = acc0[n];
            part[(size_t)(chunk * 4 + n) * MM + r1] = acc1[n];
        }
    } else {
#pragma unroll
        for (int n = 0; n < NK; n++) {
            atomicAdd(&yr[n * MM + r0], acc0[n].x);
            atomicAdd(&yi[n * MM + r0], acc0[n].y);
            atomicAdd(&yr[n * MM + r1], acc1[n].x);
            atomicAdd(&yi[n * MM + r1], acc1[n].y);
        }
    }
}

// Fused chunk-reduction + psi update, 8 lanes per (n,row).
// Lane u owns accumulator s[u] (c = u, u+8, ..., ascending: identical
// sequential order to the old per-thread s[u]); the old fixed combine tree
// ((s0+s1)+(s2+s3))+((s4+s5)+(s6+s7)) is reproduced exactly by 3 levels of
// shfl_xor (IEEE fp add is bitwise-commutative). 512x256 = 2048 waves,
// 16 loads per thread all independent -> one latency exposure, BW-bound.
template <int C>
__global__ __launch_bounds__(256) void reduce_update_k(float* __restrict__ ws) {
    int t = blockIdx.x * 256 + threadIdx.x;        // [0, 131072)
    int u = t & 7;                                 // accumulator index
    int item = t >> 3;                             // [0, 16384) = (n,row)
    int row = item & (MM - 1);
    int n = item >> 12;                            // 0..3
    const f2* part2 = (const f2*)(ws + OFF_PART);
    f2 s; s.x = 0.0f; s.y = 0.0f;
#pragma unroll
    for (int j = 0; j < C / 8; j++) {
        int c = u + 8 * j;
        s += part2[(size_t)(c * 4 + n) * MM + row];
    }
    // exact combine tree via butterfly (a+b bitwise == b+a)
    s.x += __shfl_xor(s.x, 1); s.y += __shfl_xor(s.y, 1);
    s.x += __shfl_xor(s.x, 2); s.y += __shfl_xor(s.y, 2);
    s.x += __shfl_xor(s.x, 4); s.y += __shfl_xor(s.y, 4);
    if (u == 0) {
        float cvw = ws[OFF_VW + row];
        float pr = ws[OFF_P0R + n * MM + row] + s.x;
        float pi = ws[OFF_P0I + n * MM + row] + s.y;
        ws[row * 12 + 4 + n] = cvw * pr;
        ws[row * 12 + 8 + n] = cvw * pi;
    }
}

// atomic-fallback update (only used if ws too small for partials)
__global__ __launch_bounds__(256) void update_fallback_k(float* __restrict__ ws) {
    int i = blockIdx.x * 256 + threadIdx.x;
    float cvw = ws[OFF_VW + i];
#pragma unroll
    for (int n = 0; n < NK; n++) {
        float pr = ws[OFF_P0R + n * MM + i] + ws[OFF_YR + n * MM + i];
        float pi = ws[OFF_P0I + n * MM + i] + ws[OFF_YI + n * MM + i];
        ws[i * 12 + 4 + n] = cvw * pr;
        ws[i * 12 + 8 + n] = cvw * pi;
        ws[OFF_YR + n * MM + i] = 0.0f;
        ws[OFF_YI + n * MM + i] = 0.0f;
    }
}

// 512 blocks: (k, obs_dir, j-half). float4 loads from the colpack.
__global__ __launch_bounds__(256) void far_k(const float* __restrict__ obs,
                                             const float* __restrict__ ws,
                                             float* __restrict__ out) {
    int kidx = (blockIdx.x >> 1) >> 6;
    int d = (blockIdx.x >> 1) & 63;
    int half = blockIdx.x & 1;
    float kk = 0.5f * (float)(kidx + 1);
    float ox = obs[3 * d], oy = obs[3 * d + 1], oz = obs[3 * d + 2];
    float fr = 0.0f, fi = 0.0f;
    for (int j = half * 2048 + threadIdx.x; j < half * 2048 + 2048; j += 256) {
        const float4* c4 = (const float4*)(ws + j * 12);
        float4 P = c4[0], AR = c4[1], AI = c4[2];
        float q = fmaf(P.z, oz, fmaf(P.y, oy, P.x * ox));
        float ar, ai;
        switch (kidx) {
            case 0: ar = AR.x; ai = AI.x; break;
            case 1: ar = AR.y; ai = AI.y; break;
            case 2: ar = AR.z; ai = AI.z; break;
            default: ar = AR.w; ai = AI.w; break;
        }
        float s, co;
        __sincosf(kk * q, &s, &co);
        fr += fmaf(ar, co,  ai * s);
        fi += fmaf(ai, co, -ar * s);
    }
#pragma unroll
    for (int off = 32; off > 0; off >>= 1) {
        fr += __shfl_down(fr, off);
        fi += __shfl_down(fi, off);
    }
    __shared__ float red[4][2];
    int wave = threadIdx.x >> 6;
    if ((threadIdx.x & 63) == 0) { red[wave][0] = fr; red[wave][1] = fi; }
    __syncthreads();
    if (threadIdx.x == 0) {
        fr = red[0][0] + red[1][0] + red[2][0] + red[3][0];
        fi = red[0][1] + red[1][1] + red[2][1] + red[3][1];
        atomicAdd(&out[(kidx * 64 + d) * 2 + 0], -fr);
        atomicAdd(&out[(kidx * 64 + d) * 2 + 1], -fi);
    }
}

extern "C" void kernel_launch(void* const* d_in, const int* in_sizes, int n_in,
                              void* d_out, int out_size, void* d_ws, size_t ws_size,
                              hipStream_t stream) {
    const float* V   = (const float*)d_in[0];
    const float* obs = (const float*)d_in[1];
    const float* pts = (const float*)d_in[2];
    const float* w   = (const float*)d_in[3];
    float* ws  = (float*)d_ws;
    float* out = (float*)d_out;

    // d_out is re-poisoned before every call: zero it (far_k accumulates)
    hipMemsetAsync(out, 0, (size_t)out_size * 4, stream);

    init_k<<<64, 64, 0, stream>>>(V, pts, w, ws);
    if (ws_size >= WS_NEED_PART) {
        for (int it = 0; it < 5; it++) {
            matvec_k<NCHUNK, true><<<dim3(NCHUNK, 8), 256, 0, stream>>>(
                ws, (f2*)(ws + OFF_PART), ws + OFF_YR, ws + OFF_YI);
            reduce_update_k<NCHUNK><<<512, 256, 0, stream>>>(ws);
        }
    } else {
        for (int it = 0; it < 5; it++) {
            matvec_k<64, false><<<dim3(64, 8), 256, 0, stream>>>(
                ws, (f2*)(ws + OFF_PART), ws + OFF_YR, ws + OFF_YI);
            update_fallback_k<<<16, 256, 0, stream>>>(ws);
        }
    }
    far_k<<<512, 256, 0, stream>>>(obs, ws, out);
}

// Round 3
// 215.216 us; speedup vs baseline: 1.0212x; 1.0007x over previous
//
#include <hip/hip_runtime.h>
#include <hip/hip_cooperative_groups.h>

// Born-series scattering, fully fused recompute-G approach.
// M=4096 pts, 4 wavenumbers (0.5,1,1.5,2), 5 Born iterations, 64 obs dirs.
// R4: bit-faithful D^2 (Gram rounding sequence) -> absmax 0.0.
// R5-R8: atomics eliminated; fused chunk-reduce.
// R9-R15: eight probes on the ~25us matvec plateau all neutral/regressed.
//   Body's serial load->D2->rsq->sincos->recurrence chain is trans-bound.
// R16: best config 219.8us. R17: reduce butterfly + init regrid (215.4us).
// R18: persistent fusion with hand-rolled spin barrier -> HSA abort.
//   Post-mortem: co-residency was assumed (capacity arithmetic), and the
//   relaxed AGENT-scope spin load can be satisfied from the spinner's own
//   non-coherent XCD L2 -> deadlock. Hand-rolled grid barriers are unsafe.
// R19: same fused structure, runtime-blessed sync: hipLaunchCooperativeKernel
//   (guarantees co-residency or errors) + cooperative_groups grid.sync()
//   (correct cross-XCD cache ops). Occupancy pre-check gates the coop path;
//   R17's passing multi-kernel pipeline kept verbatim as fallback.
//   All arithmetic sequences bit-identical to R17.
//
// ws layout (floats):
//   colpack[M][12]: x,y,z,r2, ar[4], ai[4]          (a = C * vw * psi, per k)
//   cvw[M]; p0r[4][M], p0i[4][M]; yr[4][M], yi[4][M] (fallback path only)
//   part[C][4][M] of float2                          (partials, 16MB)

#define MM 4096
#define NK 4
#define CGREEN 0.07957747154594767f   // 1/(4*pi)
#define INV2PI 0.15915494309189535f   // 1/(2*pi)

#define OFF_VW   49152
#define OFF_P0R  53248
#define OFF_P0I  69632
#define OFF_YR   86016
#define OFF_YI   102400
#define OFF_PART 118784
#define NCHUNK 128
#define NBLK 512
#define PART_FLOATS (NCHUNK * 8 * MM)
#define WS_NEED_PART ((size_t)(OFF_PART + PART_FLOATS) * 4)

namespace cg = cooperative_groups;

typedef float f2 __attribute__((ext_vector_type(2)));

__device__ __forceinline__ f2 vfma(f2 a, f2 b, f2 c) {
    f2 r; r.x = fmaf(a.x, b.x, c.x); r.y = fmaf(a.y, b.y, c.y); return r;
}

// One (point i, wavenumber n) init item; bit-identical math to R17's init_k.
__device__ __forceinline__ void init_item(int i, int n, const float* __restrict__ V,
                                          const float* __restrict__ pts,
                                          const float* __restrict__ w,
                                          float* __restrict__ ws, bool writeBase) {
#pragma clang fp contract(off)
    float x = pts[3 * i], y = pts[3 * i + 1], z = pts[3 * i + 2];
    float cvw = CGREEN * (V[i] * w[i]);
    float* cp = ws + i * 12;
    if (writeBase) {
        float xx = x * x, yy = y * y, zz = z * z;
        float r2 = (xx + yy) + zz;             // np rounding order
        cp[0] = x; cp[1] = y; cp[2] = z; cp[3] = r2;
        ws[OFF_VW + i] = cvw;
    }
    float kk = 0.5f * (float)(n + 1);
    float s, c;
    sincosf(kk * z, &s, &c);
    ws[OFF_P0R + n * MM + i] = c;
    ws[OFF_P0I + n * MM + i] = s;
    cp[4 + n] = cvw * c;
    cp[8 + n] = cvw * s;
}

// fallback-path init (R17: 64x64)
__global__ __launch_bounds__(64) void init_k(const float* __restrict__ V,
                                             const float* __restrict__ pts,
                                             const float* __restrict__ w,
                                             float* __restrict__ ws) {
    int i = blockIdx.x * 64 + threadIdx.x;
#pragma unroll
    for (int n = 0; n < NK; n++) {
        init_item(i, n, V, pts, w, ws, n == 0);
        ws[OFF_YR + n * MM + i] = 0.0f;
        ws[OFF_YI + n * MM + i] = 0.0f;
    }
}

// One column vs TWO rows; D^2/trans/recurrence packed across the row pair.
__device__ __forceinline__ void body_col2(f2 rx, f2 ry, f2 rz, f2 rr2,
                                          int r0, int r1, int jg,
                                          float4 A, float4 R, float4 I,
                                          f2 acc0[4], f2 acc1[4]) {
    // ---- bit-faithful D^2, per-element rounding == reference sequence ----
    f2 d2;
    {
#pragma clang fp contract(off)
        f2 m; m.x = rx.x * A.x; m.y = rx.y * A.x;          // rounded mul
        m = vfma(ry, (f2){A.y, A.y}, m);                   // k-order fma chain
        m = vfma(rz, (f2){A.z, A.z}, m);
        f2 r2s = rr2 + A.w;                                // rounded add
        f2 twod = 2.0f * m;                                // exact
        d2 = r2s - twod;                                   // single rounded sub
    }
    d2.x = fmaxf(d2.x, 1e-12f);
    d2.y = fmaxf(d2.y, 1e-12f);
    // ---- fast-math (proven invisible in bucketed output) ----
    float ia = __builtin_amdgcn_rsqf(d2.x);
    float ib = __builtin_amdgcn_rsqf(d2.y);
    f2 invD = {ia, ib};
    f2 rev = d2 * invD * (0.5f * INV2PI);   // angle 0.5*D in revolutions
    float sca = (jg == r0) ? 0.0f : ia;
    float scb = (jg == r1) ? 0.0f : ib;
    f2 s1, c1;
    s1.x = __builtin_amdgcn_sinf(rev.x);    // raw v_sin: sin(2*pi*x)
    c1.x = __builtin_amdgcn_cosf(rev.x);
    s1.y = __builtin_amdgcn_sinf(rev.y);
    c1.y = __builtin_amdgcn_cosf(rev.y);
    f2 c2 = vfma(c1, c1, -(s1 * s1));
    f2 s2 = 2.0f * (c1 * s1);
    f2 c3 = vfma(c2, c1, -(s2 * s1));
    f2 s3 = vfma(s2, c1, c2 * s1);
    f2 c4 = vfma(c2, c2, -(s2 * s2));
    f2 s4 = 2.0f * (c2 * s2);
#define ACC_UPD(nn, CC, SS, ZR, ZI)                                          \
    {                                                                        \
        f2 ri = {ZR, ZI}, sw = {-ZI, ZR};                                    \
        f2 t0 = CC.x * ri; t0 = vfma((f2){SS.x, SS.x}, sw, t0);              \
        acc0[nn] = vfma((f2){sca, sca}, t0, acc0[nn]);                       \
        f2 t1 = CC.y * ri; t1 = vfma((f2){SS.y, SS.y}, sw, t1);              \
        acc1[nn] = vfma((f2){scb, scb}, t1, acc1[nn]);                       \
    }
    ACC_UPD(0, c1, s1, R.x, I.x)
    ACC_UPD(1, c2, s2, R.y, I.y)
    ACC_UPD(2, c3, s3, R.z, I.z)
    ACC_UPD(3, c4, s4, R.w, I.w)
#undef ACC_UPD
}

// fallback-path matvec (R17), both variants
template <int C, bool USE_PART>
__global__ __launch_bounds__(256) void matvec_k(const float* __restrict__ cols,
                                                f2* __restrict__ part,
                                                float* __restrict__ yr,
                                                float* __restrict__ yi) {
    constexpr int TC = MM / C;
    const int chunk = blockIdx.x;
    const int rg = blockIdx.y;
    const int r0 = rg * 512 + threadIdx.x;
    const int r1 = r0 + 256;
    const float4 rowA = *(const float4*)&cols[r0 * 12];
    const float4 rowB = *(const float4*)&cols[r1 * 12];
    const f2 rx = {rowA.x, rowB.x}, ry = {rowA.y, rowB.y};
    const f2 rz = {rowA.z, rowB.z}, rr2 = {rowA.w, rowB.w};
    f2 acc0[4], acc1[4];
#pragma unroll
    for (int i = 0; i < 4; i++) {
        acc0[i].x = 0.0f; acc0[i].y = 0.0f;
        acc1[i].x = 0.0f; acc1[i].y = 0.0f;
    }
    const int jg0 = chunk * TC;
    const float* colbase = cols + (size_t)jg0 * 12;
#pragma unroll 4
    for (int j = 0; j < TC; j++) {
        const float4* cp = (const float4*)(colbase + j * 12);
        float4 A = cp[0], R = cp[1], I = cp[2];
        body_col2(rx, ry, rz, rr2, r0, r1, jg0 + j, A, R, I, acc0, acc1);
    }
    if (USE_PART) {
#pragma unroll
        for (int n = 0; n < NK; n++) {
            part[(size_t)(chunk * 4 + n) * MM + r0] = acc0[n];
            part[(size_t)(chunk * 4 + n) * MM + r1] = acc1[n];
        }
    } else {
#pragma unroll
        for (int n = 0; n < NK; n++) {
            atomicAdd(&yr[n * MM + r0], acc0[n].x);
            atomicAdd(&yi[n * MM + r0], acc0[n].y);
            atomicAdd(&yr[n * MM + r1], acc1[n].x);
            atomicAdd(&yi[n * MM + r1], acc1[n].y);
        }
    }
}

// fallback-path reduce (R17: 8-lane butterfly)
template <int C>
__global__ __launch_bounds__(256) void reduce_update_k(float* __restrict__ ws) {
    int t = blockIdx.x * 256 + threadIdx.x;        // [0, 131072)
    int u = t & 7;
    int item = t >> 3;
    int row = item & (MM - 1);
    int n = item >> 12;
    const f2* part2 = (const f2*)(ws + OFF_PART);
    f2 s; s.x = 0.0f; s.y = 0.0f;
#pragma unroll
    for (int j = 0; j < C / 8; j++) {
        int c = u + 8 * j;
        s += part2[(size_t)(c * 4 + n) * MM + row];
    }
    s.x += __shfl_xor(s.x, 1); s.y += __shfl_xor(s.y, 1);
    s.x += __shfl_xor(s.x, 2); s.y += __shfl_xor(s.y, 2);
    s.x += __shfl_xor(s.x, 4); s.y += __shfl_xor(s.y, 4);
    if (u == 0) {
        float cvw = ws[OFF_VW + row];
        float pr = ws[OFF_P0R + n * MM + row] + s.x;
        float pi = ws[OFF_P0I + n * MM + row] + s.y;
        ws[row * 12 + 4 + n] = cvw * pr;
        ws[row * 12 + 8 + n] = cvw * pi;
    }
}

// fallback-path update (atomic variant)
__global__ __launch_bounds__(256) void update_fallback_k(float* __restrict__ ws) {
    int i = blockIdx.x * 256 + threadIdx.x;
    float cvw = ws[OFF_VW + i];
#pragma unroll
    for (int n = 0; n < NK; n++) {
        float pr = ws[OFF_P0R + n * MM + i] + ws[OFF_YR + n * MM + i];
        float pi = ws[OFF_P0I + n * MM + i] + ws[OFF_YI + n * MM + i];
        ws[i * 12 + 4 + n] = cvw * pr;
        ws[i * 12 + 8 + n] = cvw * pi;
        ws[OFF_YR + n * MM + i] = 0.0f;
        ws[OFF_YI + n * MM + i] = 0.0f;
    }
}

// fallback-path far field
__global__ __launch_bounds__(256) void far_k(const float* __restrict__ obs,
                                             const float* __restrict__ ws,
                                             float* __restrict__ out) {
    int kidx = (blockIdx.x >> 1) >> 6;
    int d = (blockIdx.x >> 1) & 63;
    int half = blockIdx.x & 1;
    float kk = 0.5f * (float)(kidx + 1);
    float ox = obs[3 * d], oy = obs[3 * d + 1], oz = obs[3 * d + 2];
    float fr = 0.0f, fi = 0.0f;
    for (int j = half * 2048 + threadIdx.x; j < half * 2048 + 2048; j += 256) {
        const float4* c4 = (const float4*)(ws + j * 12);
        float4 P = c4[0], AR = c4[1], AI = c4[2];
        float q = fmaf(P.z, oz, fmaf(P.y, oy, P.x * ox));
        float ar, ai;
        switch (kidx) {
            case 0: ar = AR.x; ai = AI.x; break;
            case 1: ar = AR.y; ai = AI.y; break;
            case 2: ar = AR.z; ai = AI.z; break;
            default: ar = AR.w; ai = AI.w; break;
        }
        float s, co;
        __sincosf(kk * q, &s, &co);
        fr += fmaf(ar, co,  ai * s);
        fi += fmaf(ai, co, -ar * s);
    }
#pragma unroll
    for (int off = 32; off > 0; off >>= 1) {
        fr += __shfl_down(fr, off);
        fi += __shfl_down(fi, off);
    }
    __shared__ float red[4][2];
    int wave = threadIdx.x >> 6;
    if ((threadIdx.x & 63) == 0) { red[wave][0] = fr; red[wave][1] = fi; }
    __syncthreads();
    if (threadIdx.x == 0) {
        fr = red[0][0] + red[1][0] + red[2][0] + red[3][0];
        fi = red[0][1] + red[1][1] + red[2][1] + red[3][1];
        atomicAdd(&out[(kidx * 64 + d) * 2 + 0], -fr);
        atomicAdd(&out[(kidx * 64 + d) * 2 + 1], -fi);
    }
}

// ---- persistent fused kernel: init + 5x(matvec+reduce_update) + far ----
// Cooperative launch: co-residency guaranteed by the runtime; grid.sync()
// is the runtime-correct cross-XCD barrier. 512 blocks x 256 threads.
// Block = (chunk cA = bid&63, rowgroup rg = bid>>6); runs chunks cA and
// cA+64 back-to-back so the C=128 partial layout (every rounding sequence)
// is bit-identical to R17.
__global__ __launch_bounds__(256, 2) void born_k(const float* __restrict__ V,
                                                 const float* __restrict__ pts,
                                                 const float* __restrict__ w,
                                                 const float* __restrict__ obs,
                                                 float* __restrict__ ws,
                                                 float* __restrict__ out,
                                                 int out_n) {
    constexpr int C = NCHUNK;                  // 128
    constexpr int TC = MM / C;                 // 32
    cg::grid_group grid = cg::this_grid();
    const int bid = blockIdx.x;
    const int tid = bid * 256 + threadIdx.x;   // [0, 131072)

    // ---- init phase: one (i,n) item per thread for first 16384 threads ----
    if (tid < MM * NK) {
        int i = tid & (MM - 1);
        int n = tid >> 12;
        init_item(i, n, V, pts, w, ws, n == 0);
    }
    grid.sync();

    // ---- hoisted matvec row data (constant across all 5 iterations) ----
    const int cA = bid & 63;
    const int rg = bid >> 6;                   // [0,8)
    const int r0 = rg * 512 + threadIdx.x;
    const int r1 = r0 + 256;
    const float4 rowA = *(const float4*)&ws[r0 * 12];
    const float4 rowB = *(const float4*)&ws[r1 * 12];
    const f2 rx = {rowA.x, rowB.x}, ry = {rowA.y, rowB.y};
    const f2 rz = {rowA.z, rowB.z}, rr2 = {rowA.w, rowB.w};

    // ---- hoisted reduce-phase constants ----
    const int ru = tid & 7;
    const int ritem = tid >> 3;                // [0, 16384)
    const int rrow = ritem & (MM - 1);
    const int rn = ritem >> 12;                // 0..3
    const float cvw_r = ws[OFF_VW + rrow];
    const float p0r_r = ws[OFF_P0R + rn * MM + rrow];
    const float p0i_r = ws[OFF_P0I + rn * MM + rrow];

    f2* part = (f2*)(ws + OFF_PART);

    for (int it = 0; it < 5; it++) {
        // ---- matvec: chunks cA and cA+64, identical sequences to R17 ----
#pragma unroll
        for (int h = 0; h < 2; h++) {
            const int chunk = cA + 64 * h;
            f2 acc0[4], acc1[4];
#pragma unroll
            for (int i = 0; i < 4; i++) {
                acc0[i].x = 0.0f; acc0[i].y = 0.0f;
                acc1[i].x = 0.0f; acc1[i].y = 0.0f;
            }
            const int jg0 = chunk * TC;
            const float* colbase = ws + (size_t)jg0 * 12;
#pragma unroll 4
            for (int j = 0; j < TC; j++) {
                const float4* cp = (const float4*)(colbase + j * 12);
                float4 A = cp[0], R = cp[1], I = cp[2];
                body_col2(rx, ry, rz, rr2, r0, r1, jg0 + j, A, R, I, acc0, acc1);
            }
#pragma unroll
            for (int n = 0; n < NK; n++) {
                part[(size_t)(chunk * 4 + n) * MM + r0] = acc0[n];
                part[(size_t)(chunk * 4 + n) * MM + r1] = acc1[n];
            }
        }
        grid.sync();

        // ---- reduce_update: identical 8-lane/16-load/shfl-tree to R17 ----
        f2 s; s.x = 0.0f; s.y = 0.0f;
#pragma unroll
        for (int j = 0; j < C / 8; j++) {
            int c = ru + 8 * j;
            s += part[(size_t)(c * 4 + rn) * MM + rrow];
        }
        s.x += __shfl_xor(s.x, 1); s.y += __shfl_xor(s.y, 1);
        s.x += __shfl_xor(s.x, 2); s.y += __shfl_xor(s.y, 2);
        s.x += __shfl_xor(s.x, 4); s.y += __shfl_xor(s.y, 4);
        if (ru == 0) {
            float pr = p0r_r + s.x;
            float pi = p0i_r + s.y;
            ws[rrow * 12 + 4 + rn] = cvw_r * pr;
            ws[rrow * 12 + 8 + rn] = cvw_r * pi;
        }
        if (it == 4 && tid < out_n) out[tid] = 0.0f;  // zero before far atomics
        grid.sync();
    }

    // ---- far phase: identical values/mapping to far_k (512 blocks) ----
    {
        int kidx = (bid >> 1) >> 6;
        int d = (bid >> 1) & 63;
        int half = bid & 1;
        float kk = 0.5f * (float)(kidx + 1);
        float ox = obs[3 * d], oy = obs[3 * d + 1], oz = obs[3 * d + 2];
        float fr = 0.0f, fi = 0.0f;
        for (int j = half * 2048 + threadIdx.x; j < half * 2048 + 2048; j += 256) {
            const float4* c4 = (const float4*)(ws + j * 12);
            float4 P = c4[0], AR = c4[1], AI = c4[2];
            float q = fmaf(P.z, oz, fmaf(P.y, oy, P.x * ox));
            float ar, ai;
            switch (kidx) {
                case 0: ar = AR.x; ai = AI.x; break;
                case 1: ar = AR.y; ai = AI.y; break;
                case 2: ar = AR.z; ai = AI.z; break;
                default: ar = AR.w; ai = AI.w; break;
            }
            float sn, co;
            __sincosf(kk * q, &sn, &co);
            fr += fmaf(ar, co,  ai * sn);
            fi += fmaf(ai, co, -ar * sn);
        }
#pragma unroll
        for (int off = 32; off > 0; off >>= 1) {
            fr += __shfl_down(fr, off);
            fi += __shfl_down(fi, off);
        }
        __shared__ float red[4][2];
        int wave = threadIdx.x >> 6;
        if ((threadIdx.x & 63) == 0) { red[wave][0] = fr; red[wave][1] = fi; }
        __syncthreads();
        if (threadIdx.x == 0) {
            fr = red[0][0] + red[1][0] + red[2][0] + red[3][0];
            fi = red[0][1] + red[1][1] + red[2][1] + red[3][1];
            atomicAdd(&out[(kidx * 64 + d) * 2 + 0], -fr);
            atomicAdd(&out[(kidx * 64 + d) * 2 + 1], -fi);
        }
    }
}

extern "C" void kernel_launch(void* const* d_in, const int* in_sizes, int n_in,
                              void* d_out, int out_size, void* d_ws, size_t ws_size,
                              hipStream_t stream) {
    const float* V   = (const float*)d_in[0];
    const float* obs = (const float*)d_in[1];
    const float* pts = (const float*)d_in[2];
    const float* w   = (const float*)d_in[3];
    float* ws  = (float*)d_ws;
    float* out = (float*)d_out;

    if (ws_size >= WS_NEED_PART) {
        // Gate the cooperative path on an occupancy pre-check (pure query,
        // graph-capture-safe): need >= 2 blocks/CU so 512 blocks co-reside.
        static int coop_ok = -1;
        if (coop_ok < 0) {
            int nb = 0;
            hipError_t e = hipOccupancyMaxActiveBlocksPerMultiprocessor(
                &nb, born_k, 256, 0);
            coop_ok = (e == hipSuccess && nb >= 2) ? 1 : 0;
        }
        if (coop_ok == 1) {
            int out_n = out_size;
            void* args[] = {(void*)&V, (void*)&pts, (void*)&w, (void*)&obs,
                            (void*)&ws, (void*)&out, (void*)&out_n};
            hipError_t e = hipLaunchCooperativeKernel(
                born_k, dim3(NBLK), dim3(256), args, 0, stream);
            if (e == hipSuccess) return;
            coop_ok = 0;   // launch rejected -> permanent fallback
        }
        // ---- R17 fallback (measured 215.4us, passing) ----
        hipMemsetAsync(out, 0, (size_t)out_size * 4, stream);
        init_k<<<64, 64, 0, stream>>>(V, pts, w, ws);
        for (int it = 0; it < 5; it++) {
            matvec_k<NCHUNK, true><<<dim3(NCHUNK, 8), 256, 0, stream>>>(
                ws, (f2*)(ws + OFF_PART), ws + OFF_YR, ws + OFF_YI);
            reduce_update_k<NCHUNK><<<512, 256, 0, stream>>>(ws);
        }
        far_k<<<512, 256, 0, stream>>>(obs, ws, out);
    } else {
        hipMemsetAsync(out, 0, (size_t)out_size * 4, stream);
        init_k<<<64, 64, 0, stream>>>(V, pts, w, ws);
        for (int it = 0; it < 5; it++) {
            matvec_k<64, false><<<dim3(64, 8), 256, 0, stream>>>(
                ws, (f2*)(ws + OFF_PART), ws + OFF_YR, ws + OFF_YI);
            update_fallback_k<<<16, 256, 0, stream>>>(ws);
        }
        far_k<<<512, 256, 0, stream>>>(obs, ws, out);
    }
}